// Round 16
// baseline (99.061 us; speedup 1.0000x reference)
//
#include <hip/hip_runtime.h>

// HyperLayer: y[b, f0/c0] += v * w0 * (wf1*x[b,f1] + wc1*x[b,c1])
// B=16, N=262144, DIM=8192.
// R16: single-kernel structure. R15's controllable time ~21.5us of 98.8
// (the rest is harness ws-poison at 81% HBM peak). Cut the last reducible
// stage: drop partials+reduce kernel, flush LDS fixed-point accumulator
// straight to y with coalesced no-return global f32 atomics (R1 measured
// 4.2M such atomics ~6us; here 2.1M). y pre-zeroed by a 512KB memset.
// Core (from R13/R14 wins): LDS x-row gather (scattered ds_read ~free) +
// int32 fixed-point ds_add_u32 accumulator (ds_add_f32 is serialized
// ~230cyc/wave-op -- the R1-R11 50us wall).

#define BATCH 16
#define NPTS 262144
#define DIM 8192
#define SPLITS 16
#define PTS_PER_BLOCK (NPTS / SPLITS)   // 16384
#define BLOCK 1024

#define FP_SCALE 4194304.0f             // 2^22
#define FP_INV   (1.0f / 4194304.0f)

__global__ __launch_bounds__(BLOCK, 8) void hyper_scatter_kernel(
    const float* __restrict__ x,    // [B, DIM]
    const float* __restrict__ ri,   // [B, N, 2]
    const float* __restrict__ rv,   // [B, N]
    float* __restrict__ y)          // [B, DIM], pre-zeroed
{
    __shared__ float        x_s[DIM];   // 32 KB staged x row (LDS gather)
    __shared__ unsigned int S_s[DIM];   // 32 KB fixed-point accumulators

    const int tid   = threadIdx.x;
    const int split = blockIdx.x;
    const int b     = blockIdx.y;

    const float4* x4 = (const float4*)(x + (size_t)b * DIM);
    float4* xs4 = (float4*)x_s;
    uint4*  ss4 = (uint4*)S_s;
    #pragma unroll
    for (int i = tid; i < DIM / 4; i += BLOCK) {
        xs4[i] = x4[i];
        ss4[i] = make_uint4(0u, 0u, 0u, 0u);
    }
    __syncthreads();

    const size_t base = (size_t)b * NPTS + (size_t)split * PTS_PER_BLOCK;
    const float2* idx2 = (const float2*)ri + base;
    const float*  val  = rv + base;

    #pragma unroll 4
    for (int i = tid; i < PTS_PER_BLOCK; i += BLOCK) {
        float2 r = idx2[i];
        float v  = val[i];

        // frac-based corner weights; preserves reference's integral-index
        // double count (frac==0 -> both weights 1, same slot).
        float f0 = floorf(r.x);
        float fr0 = r.x - f0;
        float wf0 = 1.0f - fr0;
        bool  int0 = (fr0 == 0.0f);
        float wc0 = int0 ? 1.0f : fr0;
        int   i0f = (int)f0;
        int   i0c = i0f + (int0 ? 0 : 1);

        float f1 = floorf(r.y);
        float fr1 = r.y - f1;
        float wf1 = 1.0f - fr1;
        bool  int1 = (fr1 == 0.0f);
        float wc1 = int1 ? 1.0f : fr1;
        int   i1f = (int)f1;
        int   i1c = i1f + (int1 ? 0 : 1);

        // Scattered LDS gather (near-free).
        float xa = x_s[i1f];
        float xb = x_s[i1c];

        float vg = v * (wf1 * xa + wc1 * xb);
        // Fixed-point integer LDS atomics (per-bank full-rate; wraparound-
        // exact two's complement; |per-slot-per-block sum| << 2^31).
        int ia = __float2int_rn(wf0 * vg * FP_SCALE);
        int ib = __float2int_rn(wc0 * vg * FP_SCALE);
        atomicAdd(&S_s[i0f], (unsigned int)ia);
        atomicAdd(&S_s[i0c], (unsigned int)ib);
    }
    __syncthreads();

    // Decode fixed-point -> fp32 and flush with coalesced no-return global
    // f32 atomics (16 blocks contend per y row; 2.1M atomics total ~3us).
    float* yrow = y + (size_t)b * DIM;
    #pragma unroll
    for (int i = tid; i < DIM; i += BLOCK) {
        float p = (float)(int)S_s[i] * FP_INV;
        unsafeAtomicAdd(&yrow[i], p);
    }
}

extern "C" void kernel_launch(void* const* d_in, const int* in_sizes, int n_in,
                              void* d_out, int out_size, void* d_ws, size_t ws_size,
                              hipStream_t stream) {
    const float* x  = (const float*)d_in[0];
    const float* ri = (const float*)d_in[1];
    const float* rv = (const float*)d_in[2];
    float* y = (float*)d_out;

    // y accumulated via atomics; harness poisons it before every launch.
    hipMemsetAsync(y, 0, (size_t)out_size * sizeof(float), stream);

    dim3 grid(SPLITS, BATCH);
    hyper_scatter_kernel<<<grid, BLOCK, 0, stream>>>(x, ri, rv, y);
}